// Round 1
// baseline (130.606 us; speedup 1.0000x reference)
//
#include <hip/hip_runtime.h>
#include <math.h>

// PCEN: M[t] = (1-s)*M[t-1] + s*x[t], M[0]=x[0]
//       out = (x * (M+eps)^(-alpha) + delta)^r - delta^r,  r=0.5
//
// Chunked EMA scan with halo-approximated initial state:
//   a^W with a=0.975, W=384 is ~6e-5 -> dropping state older than W steps
//   gives output error ~3e-4, vs. 9.56e-2 threshold.

#define B_    64
#define T_    8192
#define F_    80
#define NSEQ  (B_ * F_)     // 5120 independent sequences
#define L_    512           // chunk length (T_/L_ chunks)
#define C_    (T_ / L_)     // 16
#define W_    384           // halo window; a^384 ~ 6e-5

__device__ __forceinline__ float pcen_val(float xv, float m) {
    // (m+eps)^(-0.98) via exp2/log2 (hardware trans ops)
    float g = exp2f(-0.98f * log2f(m + 1e-6f));
    float v = fmaf(xv, g, 2.0f);
    return sqrtf(v) - 1.4142135623730951f;   // delta^r = sqrt(2)
}

__global__ void __launch_bounds__(256)
pcen_kernel(const float* __restrict__ x, float* __restrict__ out) {
    const float s = 0.025f;
    const float a = 1.0f - s;   // match reference's (1.0 - s) exactly

    const int bpc   = NSEQ / 256;              // 20 blocks per chunk
    const int chunk = blockIdx.x / bpc;        // block-uniform
    const int seq   = (blockIdx.x % bpc) * 256 + threadIdx.x;
    const int b     = seq / F_;
    const int f     = seq - b * F_;

    const size_t base = (size_t)b * (T_ * F_) + f;
    const float* xp = x + base;                // element (b,t,f) at xp[t*F_]
    float*       op = out + base;

    const int t0 = chunk * L_;
    float m;
    int tstart;

    if (chunk == 0) {
        float x0 = xp[0];
        m = x0;                                // M[0] = x[0]
        op[0] = pcen_val(x0, x0);
        tstart = 1;
    } else {
        // reconstruct M[t0-1] from halo window [t0-W_, t0)
        m = 0.0f;
        const float* xh = xp + (size_t)(t0 - W_) * F_;
        #pragma unroll 8
        for (int j = 0; j < W_; ++j) {
            m = fmaf(a, m, s * (*xh));
            xh += F_;
        }
        tstart = t0;
    }

    const float* xi = xp + (size_t)tstart * F_;
    float*       oi = op + (size_t)tstart * F_;
    const int n = t0 + L_ - tstart;            // 511 or 512

    #pragma unroll 8
    for (int i = 0; i < n; ++i) {
        float xv = *xi;
        m = fmaf(a, m, s * xv);                // EMA step
        *oi = pcen_val(xv, m);
        xi += F_;
        oi += F_;
    }
}

extern "C" void kernel_launch(void* const* d_in, const int* in_sizes, int n_in,
                              void* d_out, int out_size, void* d_ws, size_t ws_size,
                              hipStream_t stream) {
    const float* x   = (const float*)d_in[0];
    float*       out = (float*)d_out;

    const int blocks = C_ * (NSEQ / 256);      // 16 * 20 = 320
    pcen_kernel<<<dim3(blocks), dim3(256), 0, stream>>>(x, out);
}